// Round 1
// baseline (340.243 us; speedup 1.0000x reference)
//
#include <hip/hip_runtime.h>

// Problem constants (fixed by setup_inputs): B=4, C=3, H=1080, W=1920, N=33
#define BB   4
#define NN   33
#define HH   1080
#define WW   1920
#define HW   (HH * WW)          // 2,073,600 (divisible by 4)
#define NNN  (NN * NN * NN)     // 35,937

// -------- Kernel 1: repack LUT [b][c][z][y][x] -> [b][z][y][x][rgb0] (float4) --------
// One float4 per LUT cell so the main kernel does ONE aligned 16B gather per corner
// instead of 3 scalar gathers. 4*35937 cells = 2.3 MB in d_ws (fits per-XCD L2).
__global__ __launch_bounds__(256) void repack_kernel(const float* __restrict__ lut,
                                                     float4* __restrict__ plut) {
    int i = blockIdx.x * blockDim.x + threadIdx.x;
    if (i >= BB * NNN) return;
    int b    = i / NNN;
    int cell = i - b * NNN;
    const float* base = lut + (size_t)b * 3 * NNN;
    float4 v;
    v.x = base[cell];            // channel 0 (R)
    v.y = base[NNN + cell];      // channel 1 (G)
    v.z = base[2 * NNN + cell];  // channel 2 (B)
    v.w = 0.0f;
    plut[i] = v;
}

// a*(1-w) + b*w  (same form as the reference for bit-level parity of rounding)
__device__ __forceinline__ float4 lerp4(float4 a, float4 b, float w) {
    float iw = 1.0f - w;
    float4 r;
    r.x = a.x * iw + b.x * w;
    r.y = a.y * iw + b.y * w;
    r.z = a.z * iw + b.z * w;
    r.w = 0.0f;
    return r;
}

__device__ __forceinline__ void sample_one(float x, float y, float z,
                                           const float4* __restrict__ lb,
                                           float& R, float& G, float& Bc) {
    // coords = clip(v * (N-1), 0, N-1)
    x = fminf(fmaxf(x * 32.0f, 0.0f), 32.0f);
    y = fminf(fmaxf(y * 32.0f, 0.0f), 32.0f);
    z = fminf(fmaxf(z * 32.0f, 0.0f), 32.0f);
    float fx = floorf(x), fy = floorf(y), fz = floorf(z);
    int x0 = (int)fx, y0 = (int)fy, z0 = (int)fz;
    int x1 = min(x0 + 1, NN - 1);
    int y1 = min(y0 + 1, NN - 1);
    int z1 = min(z0 + 1, NN - 1);
    float wx = x - fx, wy = y - fy, wz = z - fz;

    int r00 = (z0 * NN + y0) * NN;
    int r01 = (z0 * NN + y1) * NN;
    int r10 = (z1 * NN + y0) * NN;
    int r11 = (z1 * NN + y1) * NN;

    float4 c000 = lb[r00 + x0], c001 = lb[r00 + x1];
    float4 c010 = lb[r01 + x0], c011 = lb[r01 + x1];
    float4 c100 = lb[r10 + x0], c101 = lb[r10 + x1];
    float4 c110 = lb[r11 + x0], c111 = lb[r11 + x1];

    float4 c00 = lerp4(c000, c001, wx);
    float4 c01 = lerp4(c010, c011, wx);
    float4 c10 = lerp4(c100, c101, wx);
    float4 c11 = lerp4(c110, c111, wx);
    float4 c0  = lerp4(c00, c01, wy);
    float4 c1  = lerp4(c10, c11, wy);
    float4 c   = lerp4(c0, c1, wz);
    R = c.x; G = c.y; Bc = c.z;
}

// -------- Kernel 2: main trilinear apply, 4 pixels per thread --------
__global__ __launch_bounds__(256) void lut_apply_kernel(const float* __restrict__ img,
                                                        const float4* __restrict__ plut,
                                                        float* __restrict__ out) {
    const int QPB = HW / 4;  // float4 quads per batch plane
    int tid = blockIdx.x * blockDim.x + threadIdx.x;
    if (tid >= BB * QPB) return;
    int b = tid / QPB;
    int q = tid - b * QPB;

    const float* ib = img + (size_t)b * 3 * HW;
    float4 xs = ((const float4*)(ib))[q];           // channel 0 plane -> x coord
    float4 ys = ((const float4*)(ib + HW))[q];      // channel 1 plane -> y coord
    float4 zs = ((const float4*)(ib + 2 * HW))[q];  // channel 2 plane -> z coord

    const float4* lb = plut + (size_t)b * NNN;

    float xr[4] = {xs.x, xs.y, xs.z, xs.w};
    float yr[4] = {ys.x, ys.y, ys.z, ys.w};
    float zr[4] = {zs.x, zs.y, zs.z, zs.w};
    float rr[4], gg[4], bb[4];
#pragma unroll
    for (int i = 0; i < 4; ++i) {
        sample_one(xr[i], yr[i], zr[i], lb, rr[i], gg[i], bb[i]);
    }

    float* ob = out + (size_t)b * 3 * HW;
    ((float4*)(ob))[q]          = make_float4(rr[0], rr[1], rr[2], rr[3]);
    ((float4*)(ob + HW))[q]     = make_float4(gg[0], gg[1], gg[2], gg[3]);
    ((float4*)(ob + 2 * HW))[q] = make_float4(bb[0], bb[1], bb[2], bb[3]);
}

extern "C" void kernel_launch(void* const* d_in, const int* in_sizes, int n_in,
                              void* d_out, int out_size, void* d_ws, size_t ws_size,
                              hipStream_t stream) {
    const float* img = (const float*)d_in[0];   // (4,3,1080,1920) fp32
    const float* lut = (const float*)d_in[1];   // (4,3,33,33,33) fp32
    float* out = (float*)d_out;                 // (4,3,1080,1920) fp32
    float4* plut = (float4*)d_ws;               // 4*35937*16 B = 2.3 MB scratch

    int cells = BB * NNN;
    repack_kernel<<<(cells + 255) / 256, 256, 0, stream>>>(lut, plut);

    int total = BB * (HW / 4);
    lut_apply_kernel<<<(total + 255) / 256, 256, 0, stream>>>(img, plut, out);
}

// Round 3
// 282.397 us; speedup vs baseline: 1.2048x; 1.2048x over previous
//
#include <hip/hip_runtime.h>

// Problem constants (fixed by setup_inputs): B=4, C=3, H=1080, W=1920, N=33
#define BB   4
#define NN   33
#define HH   1080
#define WW   1920
#define HW   (HH * WW)          // 2,073,600 pixels per channel plane
#define NNN  (NN * NN * NN)     // 35,937 cells per batch

typedef _Float16 half2v  __attribute__((ext_vector_type(2)));
typedef float    floatx4 __attribute__((ext_vector_type(4)));   // native vec for nontemporal builtins
typedef unsigned int uintx4 __attribute__((ext_vector_type(4)));

// One LUT cell, packed: x-pair of all 3 channels in fp16.
// p[0]=(R[x],R[x+1])  p[1]=(G[x],G[x+1])  p[2]=(B[x],B[x+1])  (x+1 clamped)
union Cell {
    uintx4   v;
    half2v   p[4];
    _Float16 h[8];
};

// -------- Kernel 1: repack LUT [b][c][z][y][x] fp32 -> [b][cell] fp16 x-pairs --------
__global__ __launch_bounds__(256) void repack_kernel(const float* __restrict__ lut,
                                                     uintx4* __restrict__ plut) {
    int i = blockIdx.x * blockDim.x + threadIdx.x;
    if (i >= BB * NNN) return;
    int b    = i / NNN;
    int cell = i - b * NNN;
    int x    = cell % NN;
    int cell1 = (x < NN - 1) ? cell + 1 : cell;   // clamp x+1 at edge
    const float* base = lut + (size_t)b * 3 * NNN;
    Cell c;
    c.h[0] = (_Float16)base[cell];
    c.h[1] = (_Float16)base[cell1];
    c.h[2] = (_Float16)base[NNN + cell];
    c.h[3] = (_Float16)base[NNN + cell1];
    c.h[4] = (_Float16)base[2 * NNN + cell];
    c.h[5] = (_Float16)base[2 * NNN + cell1];
    c.h[6] = (_Float16)0.0f;
    c.h[7] = (_Float16)0.0f;
    plut[i] = c.v;
}

// x-lerp via v_dot2_f32_f16: dot((c0,c1),(1-wx,wx)) with f32 accumulate
__device__ __forceinline__ float xdot(half2v a, half2v w) {
#if __has_builtin(__builtin_amdgcn_fdot2)
    return __builtin_amdgcn_fdot2(a, w, 0.0f, false);
#else
    return (float)a.x * (float)w.x + (float)a.y * (float)w.y;
#endif
}

// -------- Kernel 2: trilinear apply, 4 pixels/thread, 4 gathers/pixel --------
__global__ __launch_bounds__(256) void lut_apply_kernel(const float* __restrict__ img,
                                                        const uintx4* __restrict__ plut,
                                                        float* __restrict__ out) {
    int b   = blockIdx.x & 3;            // XCD binding: XCD k serves batch k%4
    int blk = blockIdx.x >> 2;
    int q   = blk * 256 + threadIdx.x;   // grid sized exactly: 2025 blocks/batch

    const float* ib = img + (size_t)b * 3 * HW;
    floatx4 xs = __builtin_nontemporal_load((const floatx4*)(ib) + q);
    floatx4 ys = __builtin_nontemporal_load((const floatx4*)(ib + HW) + q);
    floatx4 zs = __builtin_nontemporal_load((const floatx4*)(ib + 2 * HW) + q);

    const uintx4* lb = plut + (size_t)b * NNN;

    float xr[4] = {xs.x, xs.y, xs.z, xs.w};
    float yr[4] = {ys.x, ys.y, ys.z, ys.w};
    float zr[4] = {zs.x, zs.y, zs.z, zs.w};

    // Phase 1: coords + indices for all 4 pixels
    int   i00[4], i01[4], i10[4], i11[4];
    float wxr[4], wyr[4], wzr[4];
#pragma unroll
    for (int i = 0; i < 4; ++i) {
        float x = fminf(fmaxf(xr[i] * 32.0f, 0.0f), 32.0f);
        float y = fminf(fmaxf(yr[i] * 32.0f, 0.0f), 32.0f);
        float z = fminf(fmaxf(zr[i] * 32.0f, 0.0f), 32.0f);
        float fx = floorf(x), fy = floorf(y), fz = floorf(z);
        int x0 = (int)fx, y0 = (int)fy, z0 = (int)fz;
        int y1 = min(y0 + 1, NN - 1);
        int z1 = min(z0 + 1, NN - 1);
        wxr[i] = x - fx; wyr[i] = y - fy; wzr[i] = z - fz;
        i00[i] = (z0 * NN + y0) * NN + x0;
        i01[i] = (z0 * NN + y1) * NN + x0;
        i10[i] = (z1 * NN + y0) * NN + x0;
        i11[i] = (z1 * NN + y1) * NN + x0;
    }

    // Phase 2: issue all 16 gathers (max MLP)
    Cell c00[4], c01[4], c10[4], c11[4];
#pragma unroll
    for (int i = 0; i < 4; ++i) {
        c00[i].v = lb[i00[i]];
        c01[i].v = lb[i01[i]];
        c10[i].v = lb[i10[i]];
        c11[i].v = lb[i11[i]];
    }

    // Phase 3: lerp tree
    float rr[4], gg[4], bb[4];
#pragma unroll
    for (int i = 0; i < 4; ++i) {
        half2v w;
        w.x = (_Float16)(1.0f - wxr[i]);
        w.y = (_Float16)wxr[i];
        float r00 = xdot(c00[i].p[0], w), g00 = xdot(c00[i].p[1], w), b00 = xdot(c00[i].p[2], w);
        float r01 = xdot(c01[i].p[0], w), g01 = xdot(c01[i].p[1], w), b01 = xdot(c01[i].p[2], w);
        float r10 = xdot(c10[i].p[0], w), g10 = xdot(c10[i].p[1], w), b10 = xdot(c10[i].p[2], w);
        float r11 = xdot(c11[i].p[0], w), g11 = xdot(c11[i].p[1], w), b11 = xdot(c11[i].p[2], w);
        float wy = wyr[i], iwy = 1.0f - wy;
        float wz = wzr[i], iwz = 1.0f - wz;
        float r0 = r00 * iwy + r01 * wy, r1 = r10 * iwy + r11 * wy;
        float g0 = g00 * iwy + g01 * wy, g1 = g10 * iwy + g11 * wy;
        float b0 = b00 * iwy + b01 * wy, b1 = b10 * iwy + b11 * wy;
        rr[i] = r0 * iwz + r1 * wz;
        gg[i] = g0 * iwz + g1 * wz;
        bb[i] = b0 * iwz + b1 * wz;
    }

    float* ob = out + (size_t)b * 3 * HW;
    floatx4 ro = {rr[0], rr[1], rr[2], rr[3]};
    floatx4 go = {gg[0], gg[1], gg[2], gg[3]};
    floatx4 bo = {bb[0], bb[1], bb[2], bb[3]};
    __builtin_nontemporal_store(ro, (floatx4*)(ob) + q);
    __builtin_nontemporal_store(go, (floatx4*)(ob + HW) + q);
    __builtin_nontemporal_store(bo, (floatx4*)(ob + 2 * HW) + q);
}

extern "C" void kernel_launch(void* const* d_in, const int* in_sizes, int n_in,
                              void* d_out, int out_size, void* d_ws, size_t ws_size,
                              hipStream_t stream) {
    const float* img = (const float*)d_in[0];   // (4,3,1080,1920) fp32
    const float* lut = (const float*)d_in[1];   // (4,3,33,33,33) fp32
    float* out = (float*)d_out;                 // (4,3,1080,1920) fp32
    uintx4* plut = (uintx4*)d_ws;               // 4*35937*16 B = 2.3 MB scratch

    int cells = BB * NNN;
    repack_kernel<<<(cells + 255) / 256, 256, 0, stream>>>(lut, plut);

    // 2025 blocks per batch * 4 batches; batch = blockIdx % 4 (XCD-bound)
    int blocks = BB * ((HW / 4) / 256);
    lut_apply_kernel<<<blocks, 256, 0, stream>>>(img, plut, out);
}

// Round 4
// 233.572 us; speedup vs baseline: 1.4567x; 1.2090x over previous
//
#include <hip/hip_runtime.h>

// Problem constants (fixed by setup_inputs): B=4, C=3, H=1080, W=1920, N=33
#define BB   4
#define NN   33
#define HH   1080
#define WW   1920
#define HW   (HH * WW)          // 2,073,600 pixels per channel plane
#define NNN  (NN * NN * NN)     // 35,937 cells per batch

typedef _Float16 half2v  __attribute__((ext_vector_type(2)));
typedef float    floatx4 __attribute__((ext_vector_type(4)));
typedef unsigned int uintx4 __attribute__((ext_vector_type(4)));

// One LUT cell = full 2x2x2 neighborhood, fp16, 48B used of 64B (line-aligned).
// p[0..2]  = (y0,z0) R/G/B x-pairs   p[3..5]  = (y1,z0)
// p[6..8]  = (y0,z1)                 p[9..11] = (y1,z1)
union Brick {
    uintx4   v[3];
    half2v   p[12];
    _Float16 h[24];
};

// -------- Kernel 1: repack LUT -> per-cell 2x2x2 fp16 bricks (64B stride) --------
__global__ __launch_bounds__(256) void repack_kernel(const float* __restrict__ lut,
                                                     uintx4* __restrict__ plut) {
    int i = blockIdx.x * blockDim.x + threadIdx.x;
    if (i >= BB * NNN) return;
    int b    = i / NNN;
    int cell = i - b * NNN;
    int x = cell % NN;
    int t = cell / NN;
    int y = t % NN;
    int z = t / NN;
    int x1 = min(x + 1, NN - 1);
    int y1 = min(y + 1, NN - 1);
    int z1 = min(z + 1, NN - 1);

    const float* base = lut + (size_t)b * 3 * NNN;
    int r00 = (z  * NN + y ) * NN;
    int r01 = (z  * NN + y1) * NN;
    int r10 = (z1 * NN + y ) * NN;
    int r11 = (z1 * NN + y1) * NN;
    int rows[4] = {r00, r01, r10, r11};

    Brick br;
#pragma unroll
    for (int corner = 0; corner < 4; ++corner) {
        int r = rows[corner];
#pragma unroll
        for (int c = 0; c < 3; ++c) {
            const float* cb = base + (size_t)c * NNN;
            half2v pr;
            pr.x = (_Float16)cb[r + x];
            pr.y = (_Float16)cb[r + x1];
            br.p[corner * 3 + c] = pr;
        }
    }
    uintx4* dst = plut + (size_t)i * 4;   // 64B stride
    dst[0] = br.v[0];
    dst[1] = br.v[1];
    dst[2] = br.v[2];
    uintx4 zero = {0, 0, 0, 0};
    dst[3] = zero;                        // pad to 64B
}

// x-lerp via v_dot2_f32_f16: dot((c0,c1),(1-wx,wx)) with f32 accumulate
__device__ __forceinline__ float xdot(half2v a, half2v w) {
#if __has_builtin(__builtin_amdgcn_fdot2)
    return __builtin_amdgcn_fdot2(a, w, 0.0f, false);
#else
    return (float)a.x * (float)w.x + (float)a.y * (float)w.y;
#endif
}

// -------- Kernel 2: trilinear apply, 4 pixels/thread, ONE brick gather/pixel --------
__global__ __launch_bounds__(256) void lut_apply_kernel(const float* __restrict__ img,
                                                        const uintx4* __restrict__ plut,
                                                        float* __restrict__ out) {
    int b   = blockIdx.x & 3;            // XCD binding: XCD k serves batch k%4
    int blk = blockIdx.x >> 2;
    int q   = blk * 256 + threadIdx.x;   // grid sized exactly: 2025 blocks/batch

    const float* ib = img + (size_t)b * 3 * HW;
    floatx4 xs = __builtin_nontemporal_load((const floatx4*)(ib) + q);
    floatx4 ys = __builtin_nontemporal_load((const floatx4*)(ib + HW) + q);
    floatx4 zs = __builtin_nontemporal_load((const floatx4*)(ib + 2 * HW) + q);

    const uintx4* lb = plut + (size_t)b * NNN * 4;

    float xr[4] = {xs.x, xs.y, xs.z, xs.w};
    float yr[4] = {ys.x, ys.y, ys.z, ys.w};
    float zr[4] = {zs.x, zs.y, zs.z, zs.w};

    // Phase 1: coords + cell indices for all 4 pixels
    int   cell[4];
    float wxr[4], wyr[4], wzr[4];
#pragma unroll
    for (int i = 0; i < 4; ++i) {
        float x = fminf(fmaxf(xr[i] * 32.0f, 0.0f), 32.0f);
        float y = fminf(fmaxf(yr[i] * 32.0f, 0.0f), 32.0f);
        float z = fminf(fmaxf(zr[i] * 32.0f, 0.0f), 32.0f);
        float fx = floorf(x), fy = floorf(y), fz = floorf(z);
        int x0 = (int)fx, y0 = (int)fy, z0 = (int)fz;
        wxr[i] = x - fx; wyr[i] = y - fy; wzr[i] = z - fz;
        cell[i] = (z0 * NN + y0) * NN + x0;
    }

    // Phase 2: one 48B brick gather per pixel (3 dwordx4, same 64B-aligned cell)
    Brick br[4];
#pragma unroll
    for (int i = 0; i < 4; ++i) {
        const uintx4* cp = lb + (size_t)cell[i] * 4;
        br[i].v[0] = cp[0];
        br[i].v[1] = cp[1];
        br[i].v[2] = cp[2];
    }

    // Phase 3: lerp tree
    float rr[4], gg[4], bb[4];
#pragma unroll
    for (int i = 0; i < 4; ++i) {
        half2v w;
        w.x = (_Float16)(1.0f - wxr[i]);
        w.y = (_Float16)wxr[i];
        float r00 = xdot(br[i].p[0],  w), g00 = xdot(br[i].p[1],  w), b00 = xdot(br[i].p[2],  w);
        float r01 = xdot(br[i].p[3],  w), g01 = xdot(br[i].p[4],  w), b01 = xdot(br[i].p[5],  w);
        float r10 = xdot(br[i].p[6],  w), g10 = xdot(br[i].p[7],  w), b10 = xdot(br[i].p[8],  w);
        float r11 = xdot(br[i].p[9],  w), g11 = xdot(br[i].p[10], w), b11 = xdot(br[i].p[11], w);
        float wy = wyr[i], iwy = 1.0f - wy;
        float wz = wzr[i], iwz = 1.0f - wz;
        float r0 = r00 * iwy + r01 * wy, r1 = r10 * iwy + r11 * wy;
        float g0 = g00 * iwy + g01 * wy, g1 = g10 * iwy + g11 * wy;
        float b0 = b00 * iwy + b01 * wy, b1 = b10 * iwy + b11 * wy;
        rr[i] = r0 * iwz + r1 * wz;
        gg[i] = g0 * iwz + g1 * wz;
        bb[i] = b0 * iwz + b1 * wz;
    }

    float* ob = out + (size_t)b * 3 * HW;
    floatx4 ro = {rr[0], rr[1], rr[2], rr[3]};
    floatx4 go = {gg[0], gg[1], gg[2], gg[3]};
    floatx4 bo = {bb[0], bb[1], bb[2], bb[3]};
    __builtin_nontemporal_store(ro, (floatx4*)(ob) + q);
    __builtin_nontemporal_store(go, (floatx4*)(ob + HW) + q);
    __builtin_nontemporal_store(bo, (floatx4*)(ob + 2 * HW) + q);
}

extern "C" void kernel_launch(void* const* d_in, const int* in_sizes, int n_in,
                              void* d_out, int out_size, void* d_ws, size_t ws_size,
                              hipStream_t stream) {
    const float* img = (const float*)d_in[0];   // (4,3,1080,1920) fp32
    const float* lut = (const float*)d_in[1];   // (4,3,33,33,33) fp32
    float* out = (float*)d_out;                 // (4,3,1080,1920) fp32
    uintx4* plut = (uintx4*)d_ws;               // 4*35937*64 B = 9.2 MB scratch

    int cells = BB * NNN;
    repack_kernel<<<(cells + 255) / 256, 256, 0, stream>>>(lut, plut);

    // 2025 blocks per batch * 4 batches; batch = blockIdx % 4 (XCD-bound)
    int blocks = BB * ((HW / 4) / 256);
    lut_apply_kernel<<<blocks, 256, 0, stream>>>(img, plut, out);
}